// Round 9
// baseline (209.936 us; speedup 1.0000x reference)
//
#include <hip/hip_runtime.h>
#include <hip/hip_bf16.h>
#include <cstdint>

#define NN 512
#define DD 128
#define EE 64
#define THR 0.1f
#define NCH_D 64    // dir j-chunks (512/8)
#define NCH_B 16    // bidir j-chunks (512/32)

typedef __bf16 bf16x8 __attribute__((ext_vector_type(8)));
typedef float  f32x4  __attribute__((ext_vector_type(4)));

__device__ __forceinline__ void stage16(const float* g, float* l) {
    __builtin_amdgcn_global_load_lds(
        (const __attribute__((address_space(1))) uint32_t*)g,
        (__attribute__((address_space(3))) uint32_t*)l, 16, 0, 0);
}

// ---------------------------------------------------------------------------
__global__ __launch_bounds__(256) void k_zero(float* __restrict__ p, int n)
{
    int i = blockIdx.x * 256 + threadIdx.x;
    if (i < n) p[i] = 0.f;
}

// ---------------------------------------------------------------------------
// k_pre: 5 small GEMMs (512,128)@(128,128): src, tgt, bsrc, btgt, hmid(relu)
// ---------------------------------------------------------------------------
__global__ __launch_bounds__(128) void k_pre(
    const float* __restrict__ x,
    const float* __restrict__ dw1, const float* __restrict__ bw1,
    const float* __restrict__ nw1, const float* __restrict__ nb1,
    float* __restrict__ src, float* __restrict__ tgt,
    float* __restrict__ bsrc, float* __restrict__ btgt, float* __restrict__ hmid)
{
    const int i0 = blockIdx.x * 4;
    const int h  = threadIdx.x;
    const int which = blockIdx.y;
    const float* B; float* outp;
    switch (which) {
        case 0:  B = dw1;          outp = src;  break;
        case 1:  B = dw1 + DD*DD;  outp = tgt;  break;
        case 2:  B = bw1;          outp = bsrc; break;
        case 3:  B = bw1 + DD*DD;  outp = btgt; break;
        default: B = nw1;          outp = hmid; break;
    }
    __shared__ float sx[4][DD];
    for (int idx = h; idx < 4*DD; idx += DD)
        sx[idx >> 7][idx & 127] = x[i0*DD + idx];
    __syncthreads();
    float a0=0.f, a1=0.f, a2=0.f, a3=0.f;
    for (int k = 0; k < DD; ++k) {
        float w = B[k*DD + h];
        a0 = fmaf(sx[0][k], w, a0);
        a1 = fmaf(sx[1][k], w, a1);
        a2 = fmaf(sx[2][k], w, a2);
        a3 = fmaf(sx[3][k], w, a3);
    }
    if (which == 4) {
        float bb = nb1[h];
        a0 = fmaxf(a0+bb, 0.f); a1 = fmaxf(a1+bb, 0.f);
        a2 = fmaxf(a2+bb, 0.f); a3 = fmaxf(a3+bb, 0.f);
    }
    outp[(i0+0)*DD + h] = a0;
    outp[(i0+1)*DD + h] = a1;
    outp[(i0+2)*DD + h] = a2;
    outp[(i0+3)*DD + h] = a3;
}

// ---------------------------------------------------------------------------
// k_msg: co-dispatched dir + bidir (role = blockIdx.x & 1), 1024 blocks.
//
// dir (R9): i-tile 64 x j-chunk 8. Each staged j-tile = ef[j, i0:i0+64, :] =
// 16 KB CONTIGUOUS (was 4 KB @128KB stride) — the DRAM-locality experiment.
// Double-buffered global_load_lds ring (2x16KB); 2 barriers/phase; vmcnt
// counts only stage ops (full drain before first stage). Each wave owns 2
// h-cols (nf pair) and iterates 4 i-subtiles; acc[4][2][4] fp32.
// LDS: [0,8192) ring | [8192,9216) s_src[8][128] | [9216,9728) s_wd[8][64].
// Total 38 KB -> 4 blocks/CU with __launch_bounds__(256,4).
// ---------------------------------------------------------------------------
__global__ __launch_bounds__(256, 4) void k_msg(
    const float* __restrict__ ef, const float* __restrict__ W,
    const float* __restrict__ M,
    const float* __restrict__ dw1, const float* __restrict__ db1,
    const float* __restrict__ src, const float* __restrict__ tgt,
    const float* __restrict__ bsrc, const float* __restrict__ btgt,
    const float* __restrict__ bb1,
    float* __restrict__ td_base, float* __restrict__ tb_base,
    float* __restrict__ wsum_d, float* __restrict__ wsum_b, int partial)
{
    __shared__ float smem[9728];           // 38 KB
    const int bid  = blockIdx.x;
    const int role = bid & 1;
    const int sub  = bid >> 1;             // 0..511
    const int tid  = threadIdx.x;

    if (role == 0) {
        // ------------------------------ dir ------------------------------
        const int i0    = (sub & 7) * 64;      // i-tile of 64
        const int chunk = sub >> 3;            // 0..63
        const int j0    = chunk * 8;           // j-chunk of 8
        float* stg   = smem;                   // [2][4096]
        float* s_src = smem + 8192;            // [8][128]
        float* s_wd  = smem + 9216;            // [8][64]
        const int wv   = tid >> 6;
        const int l    = tid & 63;
        const int lrow = l & 15, lhi = l >> 4;

        // staging thread-geometry: thread covers 16B slot (row=q*16+trow, sst)
        const int trow = tid >> 4;             // 0..15 (row within 16-row group)
        const int sst  = tid & 15;
        const int slog = (sst & 8) | ((sst & 7) ^ (trow & 7));  // XOR involution
        const float* gstage = ef + ((size_t)(i0 + trow))*EE + (size_t)slog*4;

        // s_src / s_wd
        ((float4*)s_src)[tid] = ((const float4*)(src + j0*DD))[tid];
        for (int idx = tid; idx < 8*64; idx += 256) {
            int jj = idx >> 6, ii = idx & 63;
            float w = fabsf(W[(size_t)(j0 + jj)*NN + i0 + ii]);
            s_wd[idx] = (w > THR) ? w : 0.0f;
        }

        // B fragments: this wave's 2 nf tiles
        bf16x8 bfrag[2][2];
        #pragma unroll
        for (int nfl = 0; nfl < 2; ++nfl)
            #pragma unroll
            for (int kf = 0; kf < 2; ++kf) {
                bf16x8 t;
                #pragma unroll
                for (int e = 0; e < 8; ++e)
                    t[e] = (__bf16)dw1[(2*DD + kf*32 + lhi*8 + e)*DD + (wv*2+nfl)*16 + lrow];
                bfrag[nfl][kf] = t;
            }
        // tgt + db1 in D-frag layout for 4 i-subtiles
        float tpre[4][2][4];
        #pragma unroll
        for (int s = 0; s < 4; ++s)
            #pragma unroll
            for (int nfl = 0; nfl < 2; ++nfl)
                #pragma unroll
                for (int r = 0; r < 4; ++r) {
                    int hh = (wv*2+nfl)*16 + lrow;
                    tpre[s][nfl][r] = tgt[(i0 + s*16 + lhi*4 + r)*DD + hh] + db1[hh];
                }

        // swizzled read offsets (floats): ro[kf*2+q]
        int ro[4];
        #pragma unroll
        for (int kf = 0; kf < 2; ++kf)
            #pragma unroll
            for (int q = 0; q < 2; ++q)
                ro[kf*2 + q] = ((kf*8) | (((lhi*2 + q) ^ (lrow & 7)) & 7)) * 4;

        float acc[4][2][4] = {};

        // drain ALL prior vmem/lds so manual vmcnt counts only stage16 ops
        asm volatile("s_waitcnt vmcnt(0) lgkmcnt(0)" ::: "memory");
        __builtin_amdgcn_sched_barrier(0);

#define STAGE(J, BUF)                                                         \
        {                                                                     \
            const float* g_ = gstage + (size_t)(j0 + (J))*NN*EE;              \
            float* l_ = stg + (BUF)*4096 + tid*4;                             \
            stage16(g_,          l_);                                         \
            stage16(g_ + 1024,   l_ + 1024);                                  \
            stage16(g_ + 2048,   l_ + 2048);                                  \
            stage16(g_ + 3072,   l_ + 3072);                                  \
        }

        STAGE(0, 0)
        __builtin_amdgcn_sched_barrier(0);
        __builtin_amdgcn_s_barrier();          // publishes s_src/s_wd too
        __builtin_amdgcn_sched_barrier(0);

#define MATH_TILE(T, BUF)                                                     \
        _Pragma("unroll")                                                     \
        for (int s = 0; s < 4; ++s) {                                         \
            const float* bufs_ = stg + (BUF)*4096 + (s*16 + lrow)*64;         \
            float4 f00 = *(const float4*)(bufs_ + ro[0]);                     \
            float4 f01 = *(const float4*)(bufs_ + ro[1]);                     \
            float4 f10 = *(const float4*)(bufs_ + ro[2]);                     \
            float4 f11 = *(const float4*)(bufs_ + ro[3]);                     \
            bf16x8 a0_, a1_;                                                  \
            a0_[0]=(__bf16)f00.x; a0_[1]=(__bf16)f00.y;                       \
            a0_[2]=(__bf16)f00.z; a0_[3]=(__bf16)f00.w;                       \
            a0_[4]=(__bf16)f01.x; a0_[5]=(__bf16)f01.y;                       \
            a0_[6]=(__bf16)f01.z; a0_[7]=(__bf16)f01.w;                       \
            a1_[0]=(__bf16)f10.x; a1_[1]=(__bf16)f10.y;                       \
            a1_[2]=(__bf16)f10.z; a1_[3]=(__bf16)f10.w;                       \
            a1_[4]=(__bf16)f11.x; a1_[5]=(__bf16)f11.y;                       \
            a1_[6]=(__bf16)f11.z; a1_[7]=(__bf16)f11.w;                       \
            float wdv[4];                                                     \
            _Pragma("unroll")                                                 \
            for (int r = 0; r < 4; ++r)                                       \
                wdv[r] = s_wd[(T)*64 + s*16 + lhi*4 + r];                     \
            _Pragma("unroll")                                                 \
            for (int nfl = 0; nfl < 2; ++nfl) {                               \
                f32x4 z = {0.f, 0.f, 0.f, 0.f};                               \
                z = __builtin_amdgcn_mfma_f32_16x16x32_bf16(a0_, bfrag[nfl][0], z, 0, 0, 0); \
                z = __builtin_amdgcn_mfma_f32_16x16x32_bf16(a1_, bfrag[nfl][1], z, 0, 0, 0); \
                float sv = s_src[(T)*DD + (wv*2+nfl)*16 + lrow];              \
                _Pragma("unroll")                                             \
                for (int r = 0; r < 4; ++r) {                                 \
                    float v = z[r] + sv + tpre[s][nfl][r];                    \
                    acc[s][nfl][r] = fmaf(wdv[r], fmaxf(v, 0.f), acc[s][nfl][r]); \
                }                                                             \
            }                                                                 \
        }

        #pragma unroll
        for (int j = 0; j < 8; ++j) {
            if (j > 0) {
                __builtin_amdgcn_sched_barrier(0);
                __builtin_amdgcn_s_barrier();  // readers of buf (j+1)&1 done
                __builtin_amdgcn_sched_barrier(0);
            }
            if (j < 7) STAGE(j + 1, (j + 1) & 1)
            if (j < 7) asm volatile("s_waitcnt vmcnt(4)" ::: "memory");
            else       asm volatile("s_waitcnt vmcnt(0)" ::: "memory");
            __builtin_amdgcn_sched_barrier(0);
            __builtin_amdgcn_s_barrier();      // whole tile j in LDS
            __builtin_amdgcn_sched_barrier(0);
            MATH_TILE(j, j & 1)
        }
#undef STAGE
#undef MATH_TILE

        // epilogue: direct stores (wave owns disjoint (i,h) range)
        float* dst = td_base + (partial ? (size_t)chunk * (NN*DD) : 0);
        #pragma unroll
        for (int s = 0; s < 4; ++s)
            #pragma unroll
            for (int nfl = 0; nfl < 2; ++nfl)
                #pragma unroll
                for (int r = 0; r < 4; ++r) {
                    int o = (i0 + s*16 + lhi*4 + r)*DD + (wv*2+nfl)*16 + lrow;
                    if (partial) dst[o] = acc[s][nfl][r];
                    else         atomicAdd(&dst[o], acc[s][nfl][r]);
                }
        if (tid < 64) {
            float s = 0.f;
            #pragma unroll
            for (int jj = 0; jj < 8; ++jj) s += s_wd[jj*64 + tid];
            if (partial) wsum_d[chunk * NN + i0 + tid] = s;
            else         atomicAdd(&wsum_d[i0 + tid], s);
        }
    } else {
        // ----------------------------- bidir -----------------------------
        const int i0    = (sub & 31) * 16;
        const int jbase = (sub >> 5) * 32;
        const int chunk = sub >> 5;
        float* s_wb = smem;                // [16][32]
        float* s_bs = smem + 512;          // [32][128]
        const int il = tid >> 4;
        const int hg = tid & 15;

        for (int idx = tid; idx < 16*32; idx += 256) {
            int r = idx >> 5, jj = idx & 31;
            float m = fabsf(M[(size_t)(i0 + r)*NN + jbase + jj]);
            float w = (m > THR) ? m : 0.f;
            if (i0 + r == jbase + jj) w = 0.f;
            s_wb[idx] = w;
        }
        for (int idx = tid; idx < 32*DD/4; idx += 256)
            ((float4*)s_bs)[idx] = ((const float4*)(bsrc + jbase*DD))[idx];
        __syncthreads();

        float bt[8], acc[8] = {};
        #pragma unroll
        for (int r = 0; r < 8; ++r) {
            int hh = hg*8 + r;
            bt[r] = btgt[(i0 + il)*DD + hh] + bb1[hh];
        }
        for (int jj = 0; jj < 32; ++jj) {
            float w = s_wb[il*32 + jj];
            const float* sp = &s_bs[jj*DD + hg*8];
            float4 v0 = *(const float4*)sp;
            float4 v1 = *(const float4*)(sp + 4);
            acc[0] = fmaf(w, fmaxf(v0.x + bt[0], 0.f), acc[0]);
            acc[1] = fmaf(w, fmaxf(v0.y + bt[1], 0.f), acc[1]);
            acc[2] = fmaf(w, fmaxf(v0.z + bt[2], 0.f), acc[2]);
            acc[3] = fmaf(w, fmaxf(v0.w + bt[3], 0.f), acc[3]);
            acc[4] = fmaf(w, fmaxf(v1.x + bt[4], 0.f), acc[4]);
            acc[5] = fmaf(w, fmaxf(v1.y + bt[5], 0.f), acc[5]);
            acc[6] = fmaf(w, fmaxf(v1.z + bt[6], 0.f), acc[6]);
            acc[7] = fmaf(w, fmaxf(v1.w + bt[7], 0.f), acc[7]);
        }
        float* dst = tb_base + (partial ? (size_t)chunk * (NN*DD) : 0);
        #pragma unroll
        for (int r = 0; r < 8; ++r) {
            int o = (i0 + il)*DD + hg*8 + r;
            if (partial) dst[o] = acc[r]; else atomicAdd(&dst[o], acc[r]);
        }
        if (tid < 16) {
            float s = 0.f;
            #pragma unroll
            for (int jj = 0; jj < 32; ++jj) s += s_wb[tid*32 + jj];
            if (partial) wsum_b[chunk * NN + i0 + tid] = s;
            else         atomicAdd(&wsum_b[i0 + tid], s);
        }
    }
}

// ---------------------------------------------------------------------------
// k_final: one thread per output element, 2 rows per block, grid 256 x 256.
// Folds cd dir-chunk partials (64) + cb bidir-chunk partials (16).
// ---------------------------------------------------------------------------
__global__ __launch_bounds__(256) void k_final(
    const float* __restrict__ hmid, const float* __restrict__ nw2, const float* __restrict__ nb2,
    const float* __restrict__ td,   const float* __restrict__ dw2, const float* __restrict__ db2,
    const float* __restrict__ wsd,
    const float* __restrict__ tb,   const float* __restrict__ bw2, const float* __restrict__ bb2,
    const float* __restrict__ wsb,
    const float* __restrict__ lng,  const float* __restrict__ lnb,
    float* __restrict__ out, int cd, int cb, int wpart)
{
    const int tid = threadIdx.x;
    const int r   = tid >> 7;
    const int h   = tid & 127;
    const int row = blockIdx.x * 2 + r;
    const int o   = row * DD + h;

    __shared__ float sm[2][DD], sd[2][DD], sb[2][DD];
    __shared__ float red[4];

    float vm = hmid[o];
    float s1 = 0.f, s2 = 0.f;
    #pragma unroll 8
    for (int c = 0; c < cd; ++c) s1 += td[(size_t)c*(NN*DD) + o];
    #pragma unroll 4
    for (int c = 0; c < cb; ++c) s2 += tb[(size_t)c*(NN*DD) + o];
    sm[r][h] = vm; sd[r][h] = s1; sb[r][h] = s2;
    __syncthreads();

    float wsum_d_row, wsum_b_row;
    if (wpart) {
        float a = 0.f, b = 0.f;
        #pragma unroll 8
        for (int c = 0; c < cd; ++c) a += wsd[c*NN + row];
        #pragma unroll 4
        for (int c = 0; c < cb; ++c) b += wsb[c*NN + row];
        wsum_d_row = a; wsum_b_row = b;
    } else {
        wsum_d_row = wsd[row]; wsum_b_row = wsb[row];
    }

    float acc = nb2[h] + wsum_d_row*db2[h] + wsum_b_row*bb2[h];
    #pragma unroll 4
    for (int k = 0; k < DD; ++k) {
        acc += sm[r][k]*nw2[k*DD + h] + sd[r][k]*dw2[k*DD + h] + sb[r][k]*bw2[k*DD + h];
    }

    const int wid = tid >> 6;
    float s = acc;
    #pragma unroll
    for (int off = 32; off > 0; off >>= 1) s += __shfl_down(s, off);
    if ((tid & 63) == 0) red[wid] = s;
    __syncthreads();
    float mu = (red[2*r] + red[2*r + 1]) * (1.0f/128.0f);
    float dv = acc - mu;
    float q  = dv * dv;
    __syncthreads();
    #pragma unroll
    for (int off = 32; off > 0; off >>= 1) q += __shfl_down(q, off);
    if ((tid & 63) == 0) red[wid] = q;
    __syncthreads();
    float var = (red[2*r] + red[2*r + 1]) * (1.0f/128.0f);
    out[o] = dv * rsqrtf(var + 1e-5f) * lng[h] + lnb[h];
}

// ---------------------------------------------------------------------------
extern "C" void kernel_launch(void* const* d_in, const int* in_sizes, int n_in,
                              void* d_out, int out_size, void* d_ws, size_t ws_size,
                              hipStream_t stream)
{
    (void)in_sizes; (void)n_in; (void)out_size;
    const float* x   = (const float*)d_in[0];
    const float* W   = (const float*)d_in[1];
    const float* M   = (const float*)d_in[2];
    const float* ef  = (const float*)d_in[3];
    const float* nw1 = (const float*)d_in[4];
    const float* nb1 = (const float*)d_in[5];
    const float* nw2 = (const float*)d_in[6];
    const float* nb2 = (const float*)d_in[7];
    const float* dw1 = (const float*)d_in[8];
    const float* db1 = (const float*)d_in[9];
    const float* dw2 = (const float*)d_in[10];
    const float* db2 = (const float*)d_in[11];
    const float* bw1 = (const float*)d_in[12];
    const float* bb1 = (const float*)d_in[13];
    const float* bw2 = (const float*)d_in[14];
    const float* bb2 = (const float*)d_in[15];
    const float* lng = (const float*)d_in[16];
    const float* lnb = (const float*)d_in[17];
    float* out = (float*)d_out;
    float* ws  = (float*)d_ws;

    const size_t TD = (size_t)NN * DD;                       // 65536
    const size_t WSD_N = (size_t)NCH_D * NN;                 // 32768
    const size_t WSB_N = (size_t)NCH_B * NN;                 // 8192
    const size_t PART_FLOATS = (size_t)(NCH_D + NCH_B)*TD + WSD_N + WSB_N + 5*TD;
    const int partial = (ws_size >= PART_FLOATS * 4) ? 1 : 0;

    float *t_dir, *t_bi, *wsd, *wsb, *base;
    if (partial) {
        t_dir = ws;
        t_bi  = ws + NCH_D*TD;
        wsd   = t_bi + NCH_B*TD;
        wsb   = wsd + WSD_N;
        base  = wsb + WSB_N;
        // no zeroing needed: all partial buffers fully overwritten each call
    } else {
        t_dir = ws;
        t_bi  = ws + TD;
        wsd   = ws + 2*TD;
        wsb   = wsd + 512;
        base  = ws + 2*TD + 1024;
        int nz = (int)(2*TD + 1024);
        k_zero<<<(nz + 255)/256, 256, 0, stream>>>(ws, nz);
    }
    float* src  = base;
    float* tgt  = base + TD;
    float* bsrc = base + 2*TD;
    float* btgt = base + 3*TD;
    float* hmid = base + 4*TD;

    k_pre  <<<dim3(NN/4, 5), 128, 0, stream>>>(x, dw1, bw1, nw1, nb1,
                                               src, tgt, bsrc, btgt, hmid);
    k_msg  <<<1024, 256, 0, stream>>>(ef, W, M, dw1, db1, src, tgt,
                                      bsrc, btgt, bb1,
                                      t_dir, t_bi, wsd, wsb, partial);
    const int cd = partial ? NCH_D : 1;
    const int cb = partial ? NCH_B : 1;
    k_final<<<NN/2, 256, 0, stream>>>(hmid, nw2, nb2, t_dir, dw2, db2, wsd,
                                      t_bi, bw2, bb2, wsb, lng, lnb, out,
                                      cd, cb, partial);
}

// Round 10
// 54.687 us; speedup vs baseline: 3.8389x; 3.8389x over previous
//
#include <hip/hip_runtime.h>
#include <hip/hip_bf16.h>
#include <cstdint>

#define NN 512
#define DD 128
#define EE 64
#define THR 0.1f
#define NCHUNK 16   // 512/32 j-chunks

typedef __bf16 bf16x8 __attribute__((ext_vector_type(8)));
typedef float  f32x4  __attribute__((ext_vector_type(4)));

__device__ __forceinline__ void stage16(const float* g, float* l) {
    __builtin_amdgcn_global_load_lds(
        (const __attribute__((address_space(1))) uint32_t*)g,
        (__attribute__((address_space(3))) uint32_t*)l, 16, 0, 0);
}

// ---------------------------------------------------------------------------
// k_zero: fallback-path zeroing (only when ws too small for partial layout).
// ---------------------------------------------------------------------------
__global__ __launch_bounds__(256) void k_zero(float* __restrict__ p, int n)
{
    int i = blockIdx.x * 256 + threadIdx.x;
    if (i < n) p[i] = 0.f;
}

// ---------------------------------------------------------------------------
// k_pre: 5 small GEMMs (512,128)@(128,128): src, tgt, bsrc, btgt, hmid(relu)
// ---------------------------------------------------------------------------
__global__ __launch_bounds__(128) void k_pre(
    const float* __restrict__ x,
    const float* __restrict__ dw1, const float* __restrict__ bw1,
    const float* __restrict__ nw1, const float* __restrict__ nb1,
    float* __restrict__ src, float* __restrict__ tgt,
    float* __restrict__ bsrc, float* __restrict__ btgt, float* __restrict__ hmid)
{
    const int i0 = blockIdx.x * 4;
    const int h  = threadIdx.x;
    const int which = blockIdx.y;
    const float* B; float* outp;
    switch (which) {
        case 0:  B = dw1;          outp = src;  break;
        case 1:  B = dw1 + DD*DD;  outp = tgt;  break;
        case 2:  B = bw1;          outp = bsrc; break;
        case 3:  B = bw1 + DD*DD;  outp = btgt; break;
        default: B = nw1;          outp = hmid; break;
    }
    __shared__ float sx[4][DD];
    for (int idx = h; idx < 4*DD; idx += DD)
        sx[idx >> 7][idx & 127] = x[i0*DD + idx];
    __syncthreads();
    float a0=0.f, a1=0.f, a2=0.f, a3=0.f;
    for (int k = 0; k < DD; ++k) {
        float w = B[k*DD + h];
        a0 = fmaf(sx[0][k], w, a0);
        a1 = fmaf(sx[1][k], w, a1);
        a2 = fmaf(sx[2][k], w, a2);
        a3 = fmaf(sx[3][k], w, a3);
    }
    if (which == 4) {
        float bb = nb1[h];
        a0 = fmaxf(a0+bb, 0.f); a1 = fmaxf(a1+bb, 0.f);
        a2 = fmaxf(a2+bb, 0.f); a3 = fmaxf(a3+bb, 0.f);
    }
    outp[(i0+0)*DD + h] = a0;
    outp[(i0+1)*DD + h] = a1;
    outp[(i0+2)*DD + h] = a2;
    outp[(i0+3)*DD + h] = a3;
}

// ---------------------------------------------------------------------------
// k_msg: co-dispatched dir + bidir (role = blockIdx.x & 1).  [R7 config —
// best measured total 55.0us. R8 (50KB LDS) and R9 (64-wide i-tile) both
// regressed; the ~40us k_msg profile rows are fill-contended artifacts.]
//
// dir role: global_load_lds-staged ef pipeline.
//  - per tile j: 256 threads stage ef[j, i0:i0+16, 0:64] (4 KB) into a 4-deep
//    LDS ring with ONE global_load_lds(16B) per thread — contiguous/coalesced.
//  - counted s_waitcnt vmcnt(3) + raw s_barrier (never drain in loop).
//  - XOR swizzle: LDS dest linear, global SOURCE pre-swizzled, ds_read_b128
//    swizzled  (slot' = (slot&8) | ((slot&7) ^ (row&7))) -> ~conflict-free.
//  - 4 waves share each tile; wave w owns h-cols [w*32, w*32+32)
//    -> acc[2][4]/lane, direct global stores, no cross-wave LDS reduce.
// LDS: [0,4096) stage ring 4x1024 f | [4096,8192) s_src | [8192,8704) s_wd.
// ---------------------------------------------------------------------------
__global__ __launch_bounds__(256, 4) void k_msg(
    const float* __restrict__ ef, const float* __restrict__ W,
    const float* __restrict__ M,
    const float* __restrict__ dw1, const float* __restrict__ db1,
    const float* __restrict__ src, const float* __restrict__ tgt,
    const float* __restrict__ bsrc, const float* __restrict__ btgt,
    const float* __restrict__ bb1,
    float* __restrict__ td_base, float* __restrict__ tb_base,
    float* __restrict__ wsum_d, float* __restrict__ wsum_b, int partial)
{
    __shared__ float smem[8704];          // 34 KB
    const int bid  = blockIdx.x;
    const int role = bid & 1;
    const int sub  = bid >> 1;             // 0..511
    const int i0    = (sub & 31) * 16;     // i-tile
    const int jbase = (sub >> 5) * 32;     // j-chunk
    const int chunk = sub >> 5;
    const int tid   = threadIdx.x;

    if (role == 0) {
        // ------------------------------ dir ------------------------------
        float* stg   = smem;               // [4][1024] floats
        float* s_src = smem + 4096;        // [32][128]
        float* s_wd  = smem + 8192;        // [32][16]
        const int wv   = tid >> 6;
        const int l    = tid & 63;
        const int lrow = l & 15, lhi = l >> 4;

        // stage addressing: thread t covers stored 16B slot (row=t>>4, sst=t&15);
        // source uses the swizzle-inverse logical slot (XOR is an involution).
        const int srow = tid >> 4;
        const int sst  = tid & 15;
        const int slog = (sst & 8) | ((sst & 7) ^ (srow & 7));
        const float* gsrc0 = ef + ((size_t)jbase*NN + i0 + srow)*EE + slog*4;
        float* ldst = stg + tid*4;

        // prologue: stage tiles 0..3 (4 vmcnt units/wave)
        #pragma unroll
        for (int t = 0; t < 4; ++t)
            stage16(gsrc0 + (size_t)t*NN*EE, ldst + t*1024);

        // s_src / s_wd staging (normal path; drained by the one syncthreads)
        for (int idx = tid; idx < 32*DD/4; idx += 256)
            ((float4*)s_src)[idx] = ((const float4*)(src + jbase*DD))[idx];
        for (int idx = tid; idx < 32*16; idx += 256) {
            int jj = idx >> 4, ii = idx & 15;
            float w = fabsf(W[(size_t)(jbase + jj)*NN + i0 + ii]);
            s_wd[idx] = (w > THR) ? w : 0.0f;
        }

        // B fragments: only this wave's 2 nf tiles (16 VGPRs)
        bf16x8 bfrag[2][2];
        #pragma unroll
        for (int nfl = 0; nfl < 2; ++nfl)
            #pragma unroll
            for (int kf = 0; kf < 2; ++kf) {
                bf16x8 t;
                #pragma unroll
                for (int e = 0; e < 8; ++e)
                    t[e] = (__bf16)dw1[(2*DD + kf*32 + lhi*8 + e)*DD + (wv*2+nfl)*16 + lrow];
                bfrag[nfl][kf] = t;
            }
        float tpre[2][4];
        #pragma unroll
        for (int nfl = 0; nfl < 2; ++nfl)
            #pragma unroll
            for (int r = 0; r < 4; ++r) {
                int hh = (wv*2+nfl)*16 + lrow;
                tpre[nfl][r] = tgt[(i0 + lhi*4 + r)*DD + hh] + db1[hh];
            }

        // swizzled fragment read offsets (floats, buffer-relative)
        int ro[4];
        #pragma unroll
        for (int h2 = 0; h2 < 2; ++h2)
            #pragma unroll
            for (int q = 0; q < 2; ++q) {
                int slot = h2*8 + lhi*2 + q;
                int st = (slot & 8) | ((slot & 7) ^ (lrow & 7));
                ro[h2*2 + q] = lrow*64 + st*4;
            }

        float acc[2][4] = {};
        __syncthreads();   // publishes s_src/s_wd; drains prologue vmcnt once

#define READ_TILE(BUF)                                                        \
        {                                                                     \
            const float* buf_ = (BUF);                                        \
            float4 f0 = *(const float4*)(buf_ + ro[0]);                       \
            float4 f1 = *(const float4*)(buf_ + ro[1]);                       \
            float4 f2 = *(const float4*)(buf_ + ro[2]);                       \
            float4 f3 = *(const float4*)(buf_ + ro[3]);                       \
            af0[0]=(__bf16)f0.x; af0[1]=(__bf16)f0.y;                         \
            af0[2]=(__bf16)f0.z; af0[3]=(__bf16)f0.w;                         \
            af0[4]=(__bf16)f1.x; af0[5]=(__bf16)f1.y;                         \
            af0[6]=(__bf16)f1.z; af0[7]=(__bf16)f1.w;                         \
            af1[0]=(__bf16)f2.x; af1[1]=(__bf16)f2.y;                         \
            af1[2]=(__bf16)f2.z; af1[3]=(__bf16)f2.w;                         \
            af1[4]=(__bf16)f3.x; af1[5]=(__bf16)f3.y;                         \
            af1[6]=(__bf16)f3.z; af1[7]=(__bf16)f3.w;                         \
        }

#define MATH_TILE(T)                                                          \
        {                                                                     \
            float wdv[4];                                                     \
            _Pragma("unroll")                                                 \
            for (int r = 0; r < 4; ++r) wdv[r] = s_wd[(T)*16 + lhi*4 + r];    \
            _Pragma("unroll")                                                 \
            for (int nfl = 0; nfl < 2; ++nfl) {                               \
                f32x4 z = {0.f, 0.f, 0.f, 0.f};                               \
                z = __builtin_amdgcn_mfma_f32_16x16x32_bf16(af0, bfrag[nfl][0], z, 0, 0, 0); \
                z = __builtin_amdgcn_mfma_f32_16x16x32_bf16(af1, bfrag[nfl][1], z, 0, 0, 0); \
                float sv = s_src[(T)*DD + (wv*2+nfl)*16 + lrow];              \
                _Pragma("unroll")                                             \
                for (int r = 0; r < 4; ++r) {                                 \
                    float v = z[r] + sv + tpre[nfl][r];                       \
                    acc[nfl][r] = fmaf(wdv[r], fmaxf(v, 0.f), acc[nfl][r]);   \
                }                                                             \
            }                                                                 \
        }

        bf16x8 af0, af1;
        for (int t = 0; t < 28; ++t) {
            asm volatile("s_waitcnt vmcnt(3)" ::: "memory");
            __builtin_amdgcn_sched_barrier(0);
            __builtin_amdgcn_s_barrier();           // tile t readable
            __builtin_amdgcn_sched_barrier(0);
            READ_TILE(stg + (t & 3)*1024);
            __builtin_amdgcn_sched_barrier(0);
            __builtin_amdgcn_s_barrier();           // all waves done reading buf
            stage16(gsrc0 + (size_t)(t + 4)*NN*EE, ldst + (t & 3)*1024);
            MATH_TILE(t);
        }
        asm volatile("s_waitcnt vmcnt(0)" ::: "memory");
        __builtin_amdgcn_sched_barrier(0);
        __builtin_amdgcn_s_barrier();               // tiles 28..31 all landed
        for (int t = 28; t < 32; ++t) {
            READ_TILE(stg + (t & 3)*1024);
            MATH_TILE(t);
        }
#undef READ_TILE
#undef MATH_TILE

        // epilogue: direct global writes (no cross-wave reduce needed)
        float* dst = td_base + (partial ? (size_t)chunk * (NN*DD) : 0);
        #pragma unroll
        for (int nfl = 0; nfl < 2; ++nfl)
            #pragma unroll
            for (int r = 0; r < 4; ++r) {
                int o = (i0 + lhi*4 + r)*DD + (wv*2+nfl)*16 + lrow;
                if (partial) dst[o] = acc[nfl][r];
                else         atomicAdd(&dst[o], acc[nfl][r]);
            }
        if (tid < 16) {
            float s = 0.f;
            #pragma unroll
            for (int jj = 0; jj < 32; ++jj) s += s_wd[jj*16 + tid];
            if (partial) wsum_d[chunk * NN + i0 + tid] = s;
            else         atomicAdd(&wsum_d[i0 + tid], s);
        }
    } else {
        // ----------------------------- bidir -----------------------------
        float* s_wb = smem;                // [16][32]
        float* s_bs = smem + 512;          // [32][128]
        const int il = tid >> 4;           // i within tile
        const int hg = tid & 15;           // h-group of 8

        for (int idx = tid; idx < 16*32; idx += 256) {
            int r = idx >> 5, jj = idx & 31;
            float m = fabsf(M[(size_t)(i0 + r)*NN + jbase + jj]);
            float w = (m > THR) ? m : 0.f;
            if (i0 + r == jbase + jj) w = 0.f;   // exclude self
            s_wb[idx] = w;
        }
        for (int idx = tid; idx < 32*DD; idx += 256)
            s_bs[idx] = bsrc[jbase*DD + idx];
        __syncthreads();

        float bt[8], acc[8] = {};
        #pragma unroll
        for (int r = 0; r < 8; ++r) {
            int hh = hg*8 + r;
            bt[r] = btgt[(i0 + il)*DD + hh] + bb1[hh];
        }
        for (int jj = 0; jj < 32; ++jj) {
            float w = s_wb[il*32 + jj];
            const float* sp = &s_bs[jj*DD + hg*8];
            float4 v0 = *(const float4*)sp;
            float4 v1 = *(const float4*)(sp + 4);
            acc[0] = fmaf(w, fmaxf(v0.x + bt[0], 0.f), acc[0]);
            acc[1] = fmaf(w, fmaxf(v0.y + bt[1], 0.f), acc[1]);
            acc[2] = fmaf(w, fmaxf(v0.z + bt[2], 0.f), acc[2]);
            acc[3] = fmaf(w, fmaxf(v0.w + bt[3], 0.f), acc[3]);
            acc[4] = fmaf(w, fmaxf(v1.x + bt[4], 0.f), acc[4]);
            acc[5] = fmaf(w, fmaxf(v1.y + bt[5], 0.f), acc[5]);
            acc[6] = fmaf(w, fmaxf(v1.z + bt[6], 0.f), acc[6]);
            acc[7] = fmaf(w, fmaxf(v1.w + bt[7], 0.f), acc[7]);
        }
        float* dst = tb_base + (partial ? (size_t)chunk * (NN*DD) : 0);
        #pragma unroll
        for (int r = 0; r < 8; ++r) {
            int o = (i0 + il)*DD + hg*8 + r;
            if (partial) dst[o] = acc[r]; else atomicAdd(&dst[o], acc[r]);
        }
        if (tid < 16) {
            float s = 0.f;
            #pragma unroll
            for (int jj = 0; jj < 32; ++jj) s += s_wb[tid*32 + jj];
            if (partial) wsum_b[chunk * NN + i0 + tid] = s;
            else         atomicAdd(&wsum_b[i0 + tid], s);
        }
    }
}

// ---------------------------------------------------------------------------
// k_final: one thread per output element, 2 rows per block, grid 256 x 256.
// ---------------------------------------------------------------------------
__global__ __launch_bounds__(256) void k_final(
    const float* __restrict__ hmid, const float* __restrict__ nw2, const float* __restrict__ nb2,
    const float* __restrict__ td,   const float* __restrict__ dw2, const float* __restrict__ db2,
    const float* __restrict__ wsd,
    const float* __restrict__ tb,   const float* __restrict__ bw2, const float* __restrict__ bb2,
    const float* __restrict__ wsb,
    const float* __restrict__ lng,  const float* __restrict__ lnb,
    float* __restrict__ out, int cd, int cb, int wpart)
{
    const int tid = threadIdx.x;
    const int r   = tid >> 7;          // 0..1
    const int h   = tid & 127;
    const int row = blockIdx.x * 2 + r;
    const int o   = row * DD + h;

    __shared__ float sm[2][DD], sd[2][DD], sb[2][DD];
    __shared__ float red[4];

    float vm = hmid[o];
    float s1 = 0.f, s2 = 0.f;
    #pragma unroll 4
    for (int c = 0; c < cd; ++c) s1 += td[(size_t)c*(NN*DD) + o];
    #pragma unroll 4
    for (int c = 0; c < cb; ++c) s2 += tb[(size_t)c*(NN*DD) + o];
    sm[r][h] = vm; sd[r][h] = s1; sb[r][h] = s2;
    __syncthreads();

    float wsum_d_row, wsum_b_row;
    if (wpart) {
        float a = 0.f, b = 0.f;
        #pragma unroll
        for (int c = 0; c < NCHUNK; ++c) {
            a += wsd[c*NN + row];
            b += wsb[c*NN + row];
        }
        wsum_d_row = a; wsum_b_row = b;
    } else {
        wsum_d_row = wsd[row]; wsum_b_row = wsb[row];
    }

    float acc = nb2[h] + wsum_d_row*db2[h] + wsum_b_row*bb2[h];
    #pragma unroll 4
    for (int k = 0; k < DD; ++k) {
        acc += sm[r][k]*nw2[k*DD + h] + sd[r][k]*dw2[k*DD + h] + sb[r][k]*bw2[k*DD + h];
    }

    const int wid = tid >> 6;                    // 0..3
    float s = acc;
    #pragma unroll
    for (int off = 32; off > 0; off >>= 1) s += __shfl_down(s, off);
    if ((tid & 63) == 0) red[wid] = s;
    __syncthreads();
    float mu = (red[2*r] + red[2*r + 1]) * (1.0f/128.0f);
    float dv = acc - mu;
    float q  = dv * dv;
    __syncthreads();
    #pragma unroll
    for (int off = 32; off > 0; off >>= 1) q += __shfl_down(q, off);
    if ((tid & 63) == 0) red[wid] = q;
    __syncthreads();
    float var = (red[2*r] + red[2*r + 1]) * (1.0f/128.0f);
    out[o] = dv * rsqrtf(var + 1e-5f) * lng[h] + lnb[h];
}

// ---------------------------------------------------------------------------
extern "C" void kernel_launch(void* const* d_in, const int* in_sizes, int n_in,
                              void* d_out, int out_size, void* d_ws, size_t ws_size,
                              hipStream_t stream)
{
    (void)in_sizes; (void)n_in; (void)out_size;
    const float* x   = (const float*)d_in[0];
    const float* W   = (const float*)d_in[1];
    const float* M   = (const float*)d_in[2];
    const float* ef  = (const float*)d_in[3];
    const float* nw1 = (const float*)d_in[4];
    const float* nb1 = (const float*)d_in[5];
    const float* nw2 = (const float*)d_in[6];
    const float* nb2 = (const float*)d_in[7];
    const float* dw1 = (const float*)d_in[8];
    const float* db1 = (const float*)d_in[9];
    const float* dw2 = (const float*)d_in[10];
    const float* db2 = (const float*)d_in[11];
    const float* bw1 = (const float*)d_in[12];
    const float* bb1 = (const float*)d_in[13];
    const float* bw2 = (const float*)d_in[14];
    const float* bb2 = (const float*)d_in[15];
    const float* lng = (const float*)d_in[16];
    const float* lnb = (const float*)d_in[17];
    float* out = (float*)d_out;
    float* ws  = (float*)d_ws;

    const size_t TD = (size_t)NN * DD;                       // 65536
    const size_t WS_PART = (size_t)NCHUNK * NN;              // 8192 floats each
    const size_t PART_FLOATS = 32*TD + 2*WS_PART + 5*TD;     // ~9.8 MB
    const int partial = (ws_size >= PART_FLOATS * 4) ? 1 : 0;

    float *t_dir, *t_bi, *wsd, *wsb, *base;
    if (partial) {
        t_dir = ws;
        t_bi  = ws + 16*TD;
        wsd   = ws + 32*TD;
        wsb   = wsd + WS_PART;
        base  = wsb + WS_PART;
        // no zeroing needed: all partial buffers fully overwritten each call
    } else {
        t_dir = ws;
        t_bi  = ws + TD;
        wsd   = ws + 2*TD;
        wsb   = wsd + 512;
        base  = ws + 2*TD + 1024;
        int nz = (int)(2*TD + 1024);
        k_zero<<<(nz + 255)/256, 256, 0, stream>>>(ws, nz);
    }
    float* src  = base;
    float* tgt  = base + TD;
    float* bsrc = base + 2*TD;
    float* btgt = base + 3*TD;
    float* hmid = base + 4*TD;

    k_pre  <<<dim3(NN/4, 5), 128, 0, stream>>>(x, dw1, bw1, nw1, nb1,
                                               src, tgt, bsrc, btgt, hmid);
    k_msg  <<<1024, 256, 0, stream>>>(ef, W, M, dw1, db1, src, tgt,
                                      bsrc, btgt, bb1,
                                      t_dir, t_bi, wsd, wsb, partial);
    const int cd = partial ? NCHUNK : 1;
    k_final<<<NN/2, 256, 0, stream>>>(hmid, nw2, nb2, t_dir, dw2, db2, wsd,
                                      t_bi, bw2, bb2, wsb, lng, lnb, out,
                                      cd, cd, partial);
}